// Round 4
// baseline (321.144 us; speedup 1.0000x reference)
//
#include <hip/hip_runtime.h>

// RA_MLA_Attention — MI355X (gfx950). Round 10.
// B=1, T=2048, E=2048, H=16, D=128, L=64, RA_WINDOW=64, RA_ALPHA=0.5
//
// Round-10 changes (k_attn only; GEMMs untouched r6-proven):
//   * k_attn LDS 33792 -> 32768 B (Ps padding 72->64 + XOR chunk-swizzle):
//     5 blocks/CU resident (was 4) -- grid is exactly 5 blocks/CU, so the
//     whole kernel is co-resident, no tail. Occupancy was the limiter
//     (22%, all pipes idle).
//   * P-write via v_cvt_pk_bf16_f32 (2 instr / 4 vals, replaces hand-RNE).
//   * defer-max (T13, THR=6 in log2 units): keep old running max when
//     mloc-mrun<=6 -> al==1 -> O-rescale skips most tiles.
//   * __launch_bounds__(256,5).

#define T_ 2048
#define E_ 2048
#define H_ 16
#define D_ 128
#define L_ 64
#define NQ 1152            // fused qkv GEMM N (1024 ql | 64 k | 64 v)

typedef float  floatx4 __attribute__((ext_vector_type(4)));
typedef __bf16 bf16x8  __attribute__((ext_vector_type(8)));

__device__ __forceinline__ ushort f2b(float x){           // fp32 -> bf16 bits, RNE
  unsigned int u = __float_as_uint(x);
  u = (u + 0x7fffu + ((u >> 16) & 1u)) >> 16;
  return (ushort)u;
}
__device__ __forceinline__ float blo(unsigned int u){ return __uint_as_float(u << 16); }
__device__ __forceinline__ float bhi(unsigned int u){ return __uint_as_float(u & 0xffff0000u); }

__device__ __forceinline__ void glds16(const ushort* g, ushort* l){
#if __has_builtin(__builtin_amdgcn_global_load_lds)
  __builtin_amdgcn_global_load_lds((const __attribute__((address_space(1))) void*)g,
                                   (__attribute__((address_space(3))) void*)l, 16, 0, 0);
#else
  *(uint4*)l = *(const uint4*)g;
#endif
}

// ---------------- fused fp32 -> bf16 convert (4 tensors, 1 launch) ----------
__global__ __launch_bounds__(256)
void k_f2b4(const float* __restrict__ a, ushort* __restrict__ oa,
            const float* __restrict__ b, ushort* __restrict__ ob,
            const float* __restrict__ c, ushort* __restrict__ oc,
            const float* __restrict__ d, ushort* __restrict__ od){
  int bid = blockIdx.x; const float* src; ushort* dst; int base;
  if (bid < 4096){ src=a; dst=oa; base=bid; }
  else if (bid < 8192){ src=b; dst=ob; base=bid-4096; }
  else if (bid < 8320){ src=c; dst=oc; base=bid-8192; }
  else { src=d; dst=od; base=bid-8320; }
  int i = (base*256 + (int)threadIdx.x)*4;
  float4 v = *(const float4*)(src + i);
  ushort4 o; o.x=f2b(v.x); o.y=f2b(v.y); o.z=f2b(v.z); o.w=f2b(v.w);
  *(ushort4*)(dst + i) = o;
}

// ---------------- fold q_to_latent into Wq:  Wql[(h,l),e] (rows of Wqkvb) ----
__global__ __launch_bounds__(128)
void k_prep_wql(const float* __restrict__ Wq, const float* __restrict__ q2l,
                ushort* __restrict__ Wql){
  const int h = blockIdx.z, lh = blockIdx.y;            // l half: lh*32..lh*32+31
  const int e = blockIdx.x*128 + threadIdx.x;
  const float* qb = q2l + (size_t)h*D_*L_ + lh*32;
  float acc[32];
  #pragma unroll
  for (int i=0;i<32;++i) acc[i]=0.f;
  for (int d=0; d<128; ++d){
    float wv = Wq[(size_t)(h*128+d)*E_ + e];
    #pragma unroll
    for (int i=0;i<32;++i) acc[i] += wv*qb[(size_t)d*64 + i];
  }
  #pragma unroll
  for (int i=0;i<32;++i) Wql[(size_t)(h*64 + lh*32 + i)*E_ + e] = f2b(acc[i]);
}

// ---------------- vupT[h][d][l] = vup[h][l][d], bf16 ----------------
__global__ __launch_bounds__(256)
void k_prep_vupT(const float* __restrict__ vup, ushort* __restrict__ vupT){
  const int h = blockIdx.x, tid = threadIdx.x;
  for (int idx = tid; idx < L_*D_; idx += 256){
    int l = idx >> 7, d = idx & 127;
    vupT[(size_t)h*D_*L_ + d*64 + l] = f2b(vup[(size_t)h*L_*D_ + idx]);
  }
}

// ---------------- m97-style GEMM: C[M,N] = A[M,K] @ B[N,K]^T ----------------
// 4 waves 2x2; BM=32*MT, BN=32*NT. OB16: bf16 out with col-block scale.
template<int MT,int NT,bool OB16>
__global__ __launch_bounds__(256)
void gemm_glds(const ushort* __restrict__ A, const ushort* __restrict__ B,
               float* __restrict__ Cf, ushort* __restrict__ Cb,
               int M, int N, int K, float scale){
  constexpr int BM = 32*MT, BN = 32*NT;
  constexpr int IA = BM/64, IB = BN/64;
  __shared__ ushort As[BM*32];
  __shared__ ushort Bs[BN*32];
  const int tid = threadIdx.x, lane = tid&63, wv = tid>>6;
  const int wm = wv & 1, wn = wv >> 1;
  const int l15 = lane&15, quad = lane>>4;
  const int m0 = blockIdx.y*BM, n0 = blockIdx.x*BN;
  const float sc = (n0 < 1024) ? scale : 1.0f;     // qkv: ql cols scaled
  floatx4 acc[MT][NT] = {};
  for (int k0=0; k0<K; k0+=32){
    __syncthreads();
    #pragma unroll
    for (int j=0;j<IA;++j){
      int c = (j*4 + wv)*64 + lane; int row = c>>2, kc = (c&3)*8;
      glds16(A + (size_t)(m0+row)*K + k0 + kc, &As[c*8]);
    }
    #pragma unroll
    for (int j=0;j<IB;++j){
      int c = (j*4 + wv)*64 + lane; int row = c>>2, kc = (c&3)*8;
      glds16(B + (size_t)(n0+row)*K + k0 + kc, &Bs[c*8]);
    }
    __syncthreads();
    bf16x8 af[MT], bfr[NT];
    #pragma unroll
    for (int mi=0;mi<MT;++mi)
      af[mi] = *(const bf16x8*)(&As[(wm*MT*16 + mi*16 + l15)*32 + quad*8]);
    #pragma unroll
    for (int ni=0;ni<NT;++ni)
      bfr[ni] = *(const bf16x8*)(&Bs[(wn*NT*16 + ni*16 + l15)*32 + quad*8]);
    #pragma unroll
    for (int mi=0;mi<MT;++mi)
      #pragma unroll
      for (int ni=0;ni<NT;++ni)
        acc[mi][ni] = __builtin_amdgcn_mfma_f32_16x16x32_bf16(af[mi], bfr[ni], acc[mi][ni], 0,0,0);
  }
  #pragma unroll
  for (int mi=0;mi<MT;++mi){
    const int rb = m0 + wm*MT*16 + mi*16 + quad*4;
    #pragma unroll
    for (int ni=0;ni<NT;++ni){
      const int col = n0 + wn*NT*16 + ni*16 + l15;
      #pragma unroll
      for (int r=0;r<4;++r){
        if constexpr (OB16) Cb[(size_t)(rb+r)*N + col] = f2b(acc[mi][ni][r]*sc);
        else                Cf[(size_t)(rb+r)*N + col] = acc[mi][ni][r];
      }
    }
  }
}

// ---------------- rowsums (rsq + rsk, one launch) ----------------
__global__ __launch_bounds__(256)
void k_rowsums(const ushort* __restrict__ qkvb,
               float* __restrict__ rsq, float* __restrict__ rsk){
  int i = blockIdx.x*256 + threadIdx.x;
  const ushort* src; float* dst;
  if (i < T_*H_){
    int t = i>>4, g = i&15;
    src = qkvb + (size_t)t*NQ + g*64; dst = rsq + i;
  } else {
    int t = i - T_*H_;
    if (t >= T_) return;
    src = qkvb + (size_t)t*NQ + 1024; dst = rsk + t;
  }
  const uint4* p = (const uint4*)src;
  float s = 0.f;
  #pragma unroll
  for (int j=0;j<8;++j){
    uint4 u = p[j];
    const unsigned int uu[4] = {u.x,u.y,u.z,u.w};
    #pragma unroll
    for (int q=0;q<4;++q){ s += blo(uu[q]); s += bhi(uu[q]); }
  }
  *dst = s;
}

// ---------------- V_exp^T[h][d][t] via MFMA, register-only ----------------
__global__ __launch_bounds__(256)
void k_vexp_mfma(const ushort* __restrict__ qkvb, const ushort* __restrict__ vupT,
                 ushort* __restrict__ vexpT){
  const int h = blockIdx.y, t0 = blockIdx.x*64;
  const int tid = threadIdx.x, lane = tid&63, w = tid>>6;
  const int l15 = lane&15, quad = lane>>4;
  bf16x8 a[2][2], b[4][2];
  #pragma unroll
  for (int mt=0;mt<2;++mt)
    #pragma unroll
    for (int kk=0;kk<2;++kk)
      a[mt][kk] = *(const bf16x8*)(vupT + (size_t)h*D_*L_ + (w*32+mt*16+l15)*64 + kk*32 + quad*8);
  #pragma unroll
  for (int nt=0;nt<4;++nt)
    #pragma unroll
    for (int kk=0;kk<2;++kk)
      b[nt][kk] = *(const bf16x8*)(qkvb + (size_t)(t0+nt*16+l15)*NQ + 1088 + kk*32 + quad*8);
  floatx4 acc[2][4] = {};
  #pragma unroll
  for (int mt=0;mt<2;++mt)
    #pragma unroll
    for (int nt=0;nt<4;++nt)
      #pragma unroll
      for (int kk=0;kk<2;++kk)
        acc[mt][nt] = __builtin_amdgcn_mfma_f32_16x16x32_bf16(a[mt][kk], b[nt][kk], acc[mt][nt], 0,0,0);
  #pragma unroll
  for (int mt=0;mt<2;++mt)
    #pragma unroll
    for (int nt=0;nt<4;++nt)
      #pragma unroll
      for (int r=0;r<4;++r)
        vexpT[((size_t)h*D_ + w*32+mt*16+quad*4+r)*T_ + t0 + nt*16 + l15] = f2b(acc[mt][nt][r]);
}

// ---------------- flash attention, split-S, counted-vmcnt pipeline ---------
// Block = (head, 64-row Q-tile qt, S-chunk c of CH tiles). 4 waves.
// K/V LDS: row-major stride 64, 16B chunk c of row r stored at slot c^(r&7)
// (glds SOURCE-permuted; writes stay contiguous). Ps: unpadded [4][16][64]
// ushort with 16B chunk swizzle chunk^(l15&7) -> 32KB total, 5 blocks/CU.
__global__ __launch_bounds__(256, 5)
void k_attn(const ushort* __restrict__ qkvb,   // [T][1152] bf16
            const float*  __restrict__ rsq,    // [T][16]  (scaled rowsums)
            const float*  __restrict__ rsk,    // [T]
            const ushort* __restrict__ vexpT,  // [16][128][T] bf16
            ushort*       __restrict__ ctx,    // [T][2048] bf16
            ushort*       __restrict__ partO,  // [16][24][4] swizzled 64x128 bf16
            float*        __restrict__ partML, // [16][24][4][64][2]
            int CH){
  __shared__ ushort Ks[64*64];      // 8KB, stride 64, XOR-swizzled chunks
  __shared__ ushort Vts[128*64];    // 16KB, stride 64, XOR-swizzled chunks
  __shared__ ushort Ps[4*16*64];    // 8KB, wave-private rows, chunk-swizzled
  const int h  = blockIdx.y;
  const int bxr = (int)gridDim.x - 1 - (int)blockIdx.x;   // heavy tiles first
  int qt, c;
  if (CH == 8){
    if (bxr < 8){ qt = bxr; c = 0; }
    else if (bxr < 24){ int u = bxr-8;  qt = 8  + (u>>1); c = u&1; }
    else if (bxr < 48){ int u = bxr-24; qt = 16 + u/3;    c = u - (u/3)*3; }
    else               { int u = bxr-48; qt = 24 + (u>>2); c = u&3; }
  } else { qt = bxr; c = 0; }
  const int nct = (qt + CH) / CH;
  const int stBeg = c*CH, stEnd = min(qt, stBeg + CH - 1);
  const int t0 = qt*64;
  const int tid = threadIdx.x, lane = tid & 63, w = tid >> 6;
  const int l15 = lane & 15, quad = lane >> 4;

  auto stageK = [&](int s0k){
    #pragma unroll
    for (int j=0;j<2;++j){ int cc = tid + j*256;
      int row = cc>>3, kc = ((cc&7) ^ (row&7))*8;
      glds16(qkvb + (size_t)(s0k + row)*NQ + 1024 + kc, &Ks[cc*8]); }
  };
  auto stageV = [&](int s0v){
    #pragma unroll
    for (int j=0;j<4;++j){ int cc = tid + j*256;
      int row = cc>>3, sc2 = ((cc&7) ^ (row&7))*8;
      glds16(vexpT + ((size_t)h*128 + row)*T_ + s0v + sc2, &Vts[cc*8]); }
  };

  const int qrow = t0 + w*16 + l15;
  const bf16x8 q0 = *(const bf16x8*)(qkvb + (size_t)qrow*NQ + h*64 + quad*8);
  const bf16x8 q1 = *(const bf16x8*)(qkvb + (size_t)qrow*NQ + h*64 + 32 + quad*8);
  const float rqv = rsq[(size_t)qrow*H_ + h] * 0.5f;      // already *isl*log2e

  float mrun = -INFINITY, lrun = 0.f;
  floatx4 o[8] = {};

  stageK(stBeg*64); stageV(stBeg*64);                // prologue

  for (int st=stBeg; st<=stEnd; ++st){
    const int s0 = st*64;
    const bool more = (st < stEnd);
    // ---- K(st) landed (V(st)'s 4 loads still in flight) ----
    asm volatile("s_waitcnt vmcnt(4)" ::: "memory");
    __builtin_amdgcn_s_barrier();
    __builtin_amdgcn_sched_barrier(0);
    // ---- S^T = K Q^T : lane owns q=l15, s=jt*16+quad*4+r ----
    floatx4 sT[4] = {};
    __builtin_amdgcn_s_setprio(1);
    #pragma unroll
    for (int jt=0;jt<4;++jt){
      const int srow = jt*16 + l15, sx = srow & 7;
      bf16x8 k0f = *(const bf16x8*)(&Ks[srow*64 + (quad^sx)*8]);
      sT[jt] = __builtin_amdgcn_mfma_f32_16x16x32_bf16(k0f, q0, sT[jt], 0,0,0);
      bf16x8 k1f = *(const bf16x8*)(&Ks[srow*64 + ((4+quad)^sx)*8]);
      sT[jt] = __builtin_amdgcn_mfma_f32_16x16x32_bf16(k1f, q1, sT[jt], 0,0,0);
    }
    __builtin_amdgcn_s_setprio(0);
    __builtin_amdgcn_sched_barrier(0);
    __builtin_amdgcn_s_barrier();                  // all K reads done
    if (more) stageK(s0 + 64);                     // K(t+1) under softmax+PV
    // ---- mask + rank-1 band (edge tiles only), in place in sT ----
    float mloc = -3.0e38f;
    if (st >= qt-1){
      #pragma unroll
      for (int jt=0;jt<4;++jt){
        const float4 rk4 = *(const float4*)(rsk + s0 + jt*16 + quad*4);  // broadcast
        #pragma unroll
        for (int r=0;r<4;++r){
          const int sg = s0 + jt*16 + quad*4 + r;
          const int dd = qrow - sg;
          float x = sT[jt][r];
          x = (dd <= 64) ? x + rqv*((const float*)&rk4)[r] : x;
          x = (dd < 0)   ? -3.0e38f : x;
          sT[jt][r] = x; mloc = fmaxf(mloc, x);
        }
      }
    } else {
      #pragma unroll
      for (int jt=0;jt<4;++jt)
        #pragma unroll
        for (int r=0;r<4;++r) mloc = fmaxf(mloc, sT[jt][r]);
    }
    mloc = fmaxf(mloc, __shfl_xor(mloc, 16));
    mloc = fmaxf(mloc, __shfl_xor(mloc, 32));
    // ---- defer-max (T13): keep old max unless it grew by >6 (log2 units) --
    const float mn = (mloc - mrun <= 6.0f) ? mrun : mloc;
    const float al = exp2f(mrun - mn);             // ==1.0 when deferred
    float ss = 0.f;
    #pragma unroll
    for (int jt=0;jt<4;++jt)
      #pragma unroll
      for (int r=0;r<4;++r){
        float p = exp2f(sT[jt][r]-mn); sT[jt][r] = p; ss += p;
      }
    ss += __shfl_xor(ss, 16); ss += __shfl_xor(ss, 32);
    lrun = lrun*al + ss; mrun = mn;
    // ---- P write (wave-private rows, chunk-swizzled; no barrier needed) ----
    #pragma unroll
    for (int jt=0;jt<4;++jt){
      unsigned p01, p23;
      asm volatile("v_cvt_pk_bf16_f32 %0, %1, %2" : "=v"(p01) : "v"(sT[jt][0]), "v"(sT[jt][1]));
      asm volatile("v_cvt_pk_bf16_f32 %0, %1, %2" : "=v"(p23) : "v"(sT[jt][2]), "v"(sT[jt][3]));
      const int chunk = 2*jt + (quad>>1);
      uint2 pw2; pw2.x = p01; pw2.y = p23;
      *(uint2*)(&Ps[(w*16 + l15)*64 + ((chunk ^ (l15&7))<<3) + (quad&1)*4]) = pw2;
    }
    // ---- rescale O rows (skip when no new max anywhere in wave) ----
    if (__any(al < 1.0f)){
      float alr[4];
      #pragma unroll
      for (int r=0;r<4;++r) alr[r] = __shfl(al, quad*4 + r);
      #pragma unroll
      for (int nt=0;nt<8;++nt){
        o[nt][0]*=alr[0]; o[nt][1]*=alr[1]; o[nt][2]*=alr[2]; o[nt][3]*=alr[3];
      }
    }
    // ---- V(st) landed (K(t+1)'s 2 loads still in flight) ----
    __builtin_amdgcn_sched_barrier(0);
    if (more) asm volatile("s_waitcnt vmcnt(2)" ::: "memory");
    else      asm volatile("s_waitcnt vmcnt(0)" ::: "memory");
    __builtin_amdgcn_s_barrier();
    __builtin_amdgcn_sched_barrier(0);
    // ---- O += P V ----
    __builtin_amdgcn_s_setprio(1);
    #pragma unroll
    for (int kks=0;kks<2;++kks){
      const int ch = kks*4 + quad;
      bf16x8 pf = *(const bf16x8*)(&Ps[(w*16 + l15)*64 + ((ch ^ (l15&7))<<3)]);
      #pragma unroll
      for (int nt=0;nt<8;++nt){
        const int vrow = nt*16 + l15, vx = vrow & 7;
        bf16x8 vf = *(const bf16x8*)(&Vts[vrow*64 + ((kks*4+quad)^vx)*8]);
        o[nt] = __builtin_amdgcn_mfma_f32_16x16x32_bf16(pf, vf, o[nt], 0,0,0);
      }
    }
    __builtin_amdgcn_s_setprio(0);
    __builtin_amdgcn_sched_barrier(0);
    if (more){
      __builtin_amdgcn_s_barrier();                // all V reads done
      stageV(s0 + 64);                             // V(t+1) under next QK+softmax
    }
  }
  // ---- epilogue ----
  const float linv = 1.f/lrun;
  float lr4[4];
  #pragma unroll
  for (int r=0;r<4;++r) lr4[r] = __shfl(linv, quad*4 + r);
  if (nct == 1){
    #pragma unroll
    for (int r=0;r<4;++r){
      const int row = t0 + w*16 + quad*4 + r;
      #pragma unroll
      for (int nt=0;nt<8;++nt)
        ctx[(size_t)row*E_ + h*D_ + nt*16 + l15] = f2b(o[nt][r]*lr4[r]);
    }
  } else {
    const int slot = (h*24 + (qt-8))*4 + c;
    ushort* po = partO + (size_t)slot*8192;            // swizzled [w][nt][r][lane]
    #pragma unroll
    for (int nt=0;nt<8;++nt)
      #pragma unroll
      for (int r=0;r<4;++r)
        po[((w*8+nt)*4+r)*64 + quad*16 + l15] = f2b(o[nt][r]*lr4[r]);  // 128B/instr
    if (quad == 0){
      float2 ml; ml.x = mrun; ml.y = lrun;
      ((float2*)partML)[(size_t)slot*64 + w*16 + l15] = ml;
    }
  }
}

// ---------------- merge partials -> ctx (qt >= 8) ----------------
__global__ __launch_bounds__(256)
void k_merge(const ushort* __restrict__ partO, const float* __restrict__ partML,
             ushort* __restrict__ ctx){
  const int h = blockIdx.y, qt = 8 + blockIdx.x;
  const int nct = (qt + 8) / 8;
  const int tid = threadIdx.x;
  const int rg = tid >> 2, d0 = (tid & 3)*32;
  const int w = rg >> 4, quad = (rg >> 2) & 3, rr = rg & 3;
  const int n0 = d0 >> 4;
  const int sbase = (h*24 + (qt-8))*4;
  float m[4], l[4], M = -INFINITY;
  for (int c=0;c<4;++c){
    if (c < nct){
      float2 v = ((const float2*)partML)[(size_t)(sbase+c)*64 + rg];
      m[c]=v.x; l[c]=v.y; M = fmaxf(M, v.x);
    }
  }
  float lt = 0.f, wgt[4];
  for (int c=0;c<4;++c){
    if (c < nct){ wgt[c] = exp2f(m[c]-M)*l[c]; lt += wgt[c]; }
  }
  const float inv = 1.f/lt;
  float acc[32];
  #pragma unroll
  for (int i=0;i<32;++i) acc[i]=0.f;
  for (int c=0;c<4;++c){
    if (c >= nct) break;
    const float sc = wgt[c]*inv;
    const ushort* po = partO + (size_t)(sbase+c)*8192;
    #pragma unroll
    for (int nn=0;nn<2;++nn){
      const ushort* p2 = po + ((w*8 + n0+nn)*4 + rr)*64 + quad*16;
      uint4 u  = *(const uint4*)p2;
      uint4 u2 = *(const uint4*)(p2 + 8);
      const unsigned int uu[8] = {u.x,u.y,u.z,u.w,u2.x,u2.y,u2.z,u2.w};
      #pragma unroll
      for (int q=0;q<8;++q){
        acc[nn*16+q*2]   += sc*blo(uu[q]);
        acc[nn*16+q*2+1] += sc*bhi(uu[q]);
      }
    }
  }
  ushort* dst = ctx + (size_t)(qt*64 + rg)*E_ + h*D_ + d0;
  #pragma unroll
  for (int k=0;k<8;++k){
    ushort4 ov; ov.x=f2b(acc[k*4]); ov.y=f2b(acc[k*4+1]);
    ov.z=f2b(acc[k*4+2]); ov.w=f2b(acc[k*4+3]);
    *(ushort4*)(dst + k*4) = ov;
  }
}

// ---------------- launch ----------------
extern "C" void kernel_launch(void* const* d_in, const int* in_sizes, int n_in,
                              void* d_out, int out_size, void* d_ws, size_t ws_size,
                              hipStream_t stream) {
  const float* hs  = (const float*)d_in[0];
  const float* Wq  = (const float*)d_in[1];
  const float* Wk  = (const float*)d_in[2];
  const float* Wv  = (const float*)d_in[3];
  const float* q2l = (const float*)d_in[4];
  const float* vup = (const float*)d_in[5];
  const float* Wo  = (const float*)d_in[6];
  float* out = (float*)d_out;
  char* ws = (char*)d_ws;

  // workspace layout (bytes) — round-6 proven layout
  ushort* hsb   = (ushort*)(ws + 0);           // [2048][2048] bf16
  ushort* Wqkvb = (ushort*)(ws + 8388608);     // [1152][2048] bf16 (ql|k|v)
  ushort* Wob   = (ushort*)(ws + 13107200);    // [2048][2048] bf16
  ushort* qkvb  = (ushort*)(ws + 21495808);    // [2048][1152] bf16
  ushort* vupT  = (ushort*)(ws + 26214400);    // [16][128][64] bf16
  float*  rsqp  = (float*) (ws + 26476544);    // [2048][16]
  float*  rskp  = (float*) (ws + 26607616);    // [2048]
  ushort* vexpT = (ushort*)(ws + 26615808);    // [16][128][2048] bf16
  ushort* ctxb  = (ushort*)(ws + 35004416);    // [2048][2048] bf16
  ushort* partO = (ushort*)(ws + 43393024);    // [16][24][4] x 8192 bf16 (swizzled)
  float*  partML= (float*) (ws + 68558848);    // [16][24][4][64][2]
  const size_t NEED = 69345280;
  const int CH = (ws_size >= NEED) ? 8 : 32;

  // 1) bf16 conversions (hs, Wo, Wk, Wv) in one launch
  k_f2b4<<<8448, 256, 0, stream>>>(hs, hsb, Wo, Wob,
                                   Wk, Wqkvb + (size_t)1024*E_,
                                   Wv, Wqkvb + (size_t)1088*E_);

  // 2) weight prep
  k_prep_wql<<<dim3(16,2,16), 128, 0, stream>>>(Wq, q2l, Wqkvb);
  k_prep_vupT<<<16, 256, 0, stream>>>(vup, vupT);

  // 3) fused q_latent|k|v GEMM -> qkvb [2048][1152] (ql cols pre-scaled)
  //    64x64 tiles: 576 blocks (2.25/CU) for latency hiding
  gemm_glds<2,2,true><<<dim3(18,32), 256, 0, stream>>>(
      hsb, Wqkvb, nullptr, qkvb, T_, NQ, E_, 0.18033688f);

  // 4) rowsums (one launch)
  k_rowsums<<<136, 256, 0, stream>>>(qkvb, rsqp, rskp);

  // 5) V_exp^T via MFMA
  k_vexp_mfma<<<dim3(32,16), 256, 0, stream>>>(qkvb, vupT, vexpT);

  // 6) flash attention (split-S, pipelined) -> ctx / partials
  k_attn<<<dim3(CH==8 ? 80 : 32, 16), 256, 0, stream>>>(
      qkvb, rsqp, rskp, vexpT, ctxb, partO, partML, CH);

  // 7) merge partials
  if (CH == 8)
    k_merge<<<dim3(24,16), 256, 0, stream>>>(partO, partML, ctxb);

  // 8) out = ctx @ Wo^T (fp32 to d_out): 64x128 tiles, 512 blocks (2/CU)
  gemm_glds<2,4,false><<<dim3(16,32), 256, 0, stream>>>(
      ctxb, Wob, out, nullptr, T_, E_, E_, 1.0f);
}

// Round 5
// 272.209 us; speedup vs baseline: 1.1798x; 1.1798x over previous
//
#include <hip/hip_runtime.h>

// RA_MLA_Attention — MI355X (gfx950). Round 11.
// B=1, T=2048, E=2048, H=16, D=128, L=64, RA_WINDOW=64, RA_ALPHA=0.5
//
// Round-11 changes (post-mortem of r10):
//   * r10's __launch_bounds__(256,5) squeezed VGPR 64->48 and SPILLED the
//     o[8] flash accumulator to scratch: FETCH 31->78MB, WRITE 21->64.5MB,
//     k_attn 46->95us. Revert to (256,4) — with 64 VGPR the HW still fits
//     5 waves/SIMD, and the r10 LDS shrink (32768B: Ps unpadded +
//     chunk-swizzle) still allows 5 blocks/CU residency.
//   * Keep: cvt_pk P-write, defer-max THR=6, 32KB LDS.

#define T_ 2048
#define E_ 2048
#define H_ 16
#define D_ 128
#define L_ 64
#define NQ 1152            // fused qkv GEMM N (1024 ql | 64 k | 64 v)

typedef float  floatx4 __attribute__((ext_vector_type(4)));
typedef __bf16 bf16x8  __attribute__((ext_vector_type(8)));

__device__ __forceinline__ ushort f2b(float x){           // fp32 -> bf16 bits, RNE
  unsigned int u = __float_as_uint(x);
  u = (u + 0x7fffu + ((u >> 16) & 1u)) >> 16;
  return (ushort)u;
}
__device__ __forceinline__ float blo(unsigned int u){ return __uint_as_float(u << 16); }
__device__ __forceinline__ float bhi(unsigned int u){ return __uint_as_float(u & 0xffff0000u); }

__device__ __forceinline__ void glds16(const ushort* g, ushort* l){
#if __has_builtin(__builtin_amdgcn_global_load_lds)
  __builtin_amdgcn_global_load_lds((const __attribute__((address_space(1))) void*)g,
                                   (__attribute__((address_space(3))) void*)l, 16, 0, 0);
#else
  *(uint4*)l = *(const uint4*)g;
#endif
}

// ---------------- fused fp32 -> bf16 convert (4 tensors, 1 launch) ----------
__global__ __launch_bounds__(256)
void k_f2b4(const float* __restrict__ a, ushort* __restrict__ oa,
            const float* __restrict__ b, ushort* __restrict__ ob,
            const float* __restrict__ c, ushort* __restrict__ oc,
            const float* __restrict__ d, ushort* __restrict__ od){
  int bid = blockIdx.x; const float* src; ushort* dst; int base;
  if (bid < 4096){ src=a; dst=oa; base=bid; }
  else if (bid < 8192){ src=b; dst=ob; base=bid-4096; }
  else if (bid < 8320){ src=c; dst=oc; base=bid-8192; }
  else { src=d; dst=od; base=bid-8320; }
  int i = (base*256 + (int)threadIdx.x)*4;
  float4 v = *(const float4*)(src + i);
  ushort4 o; o.x=f2b(v.x); o.y=f2b(v.y); o.z=f2b(v.z); o.w=f2b(v.w);
  *(ushort4*)(dst + i) = o;
}

// ---------------- fold q_to_latent into Wq:  Wql[(h,l),e] (rows of Wqkvb) ----
__global__ __launch_bounds__(128)
void k_prep_wql(const float* __restrict__ Wq, const float* __restrict__ q2l,
                ushort* __restrict__ Wql){
  const int h = blockIdx.z, lh = blockIdx.y;            // l half: lh*32..lh*32+31
  const int e = blockIdx.x*128 + threadIdx.x;
  const float* qb = q2l + (size_t)h*D_*L_ + lh*32;
  float acc[32];
  #pragma unroll
  for (int i=0;i<32;++i) acc[i]=0.f;
  for (int d=0; d<128; ++d){
    float wv = Wq[(size_t)(h*128+d)*E_ + e];
    #pragma unroll
    for (int i=0;i<32;++i) acc[i] += wv*qb[(size_t)d*64 + i];
  }
  #pragma unroll
  for (int i=0;i<32;++i) Wql[(size_t)(h*64 + lh*32 + i)*E_ + e] = f2b(acc[i]);
}

// ---------------- vupT[h][d][l] = vup[h][l][d], bf16 ----------------
__global__ __launch_bounds__(256)
void k_prep_vupT(const float* __restrict__ vup, ushort* __restrict__ vupT){
  const int h = blockIdx.x, tid = threadIdx.x;
  for (int idx = tid; idx < L_*D_; idx += 256){
    int l = idx >> 7, d = idx & 127;
    vupT[(size_t)h*D_*L_ + d*64 + l] = f2b(vup[(size_t)h*L_*D_ + idx]);
  }
}

// ---------------- m97-style GEMM: C[M,N] = A[M,K] @ B[N,K]^T ----------------
// 4 waves 2x2; BM=32*MT, BN=32*NT. OB16: bf16 out with col-block scale.
template<int MT,int NT,bool OB16>
__global__ __launch_bounds__(256)
void gemm_glds(const ushort* __restrict__ A, const ushort* __restrict__ B,
               float* __restrict__ Cf, ushort* __restrict__ Cb,
               int M, int N, int K, float scale){
  constexpr int BM = 32*MT, BN = 32*NT;
  constexpr int IA = BM/64, IB = BN/64;
  __shared__ ushort As[BM*32];
  __shared__ ushort Bs[BN*32];
  const int tid = threadIdx.x, lane = tid&63, wv = tid>>6;
  const int wm = wv & 1, wn = wv >> 1;
  const int l15 = lane&15, quad = lane>>4;
  const int m0 = blockIdx.y*BM, n0 = blockIdx.x*BN;
  const float sc = (n0 < 1024) ? scale : 1.0f;     // qkv: ql cols scaled
  floatx4 acc[MT][NT] = {};
  for (int k0=0; k0<K; k0+=32){
    __syncthreads();
    #pragma unroll
    for (int j=0;j<IA;++j){
      int c = (j*4 + wv)*64 + lane; int row = c>>2, kc = (c&3)*8;
      glds16(A + (size_t)(m0+row)*K + k0 + kc, &As[c*8]);
    }
    #pragma unroll
    for (int j=0;j<IB;++j){
      int c = (j*4 + wv)*64 + lane; int row = c>>2, kc = (c&3)*8;
      glds16(B + (size_t)(n0+row)*K + k0 + kc, &Bs[c*8]);
    }
    __syncthreads();
    bf16x8 af[MT], bfr[NT];
    #pragma unroll
    for (int mi=0;mi<MT;++mi)
      af[mi] = *(const bf16x8*)(&As[(wm*MT*16 + mi*16 + l15)*32 + quad*8]);
    #pragma unroll
    for (int ni=0;ni<NT;++ni)
      bfr[ni] = *(const bf16x8*)(&Bs[(wn*NT*16 + ni*16 + l15)*32 + quad*8]);
    #pragma unroll
    for (int mi=0;mi<MT;++mi)
      #pragma unroll
      for (int ni=0;ni<NT;++ni)
        acc[mi][ni] = __builtin_amdgcn_mfma_f32_16x16x32_bf16(af[mi], bfr[ni], acc[mi][ni], 0,0,0);
  }
  #pragma unroll
  for (int mi=0;mi<MT;++mi){
    const int rb = m0 + wm*MT*16 + mi*16 + quad*4;
    #pragma unroll
    for (int ni=0;ni<NT;++ni){
      const int col = n0 + wn*NT*16 + ni*16 + l15;
      #pragma unroll
      for (int r=0;r<4;++r){
        if constexpr (OB16) Cb[(size_t)(rb+r)*N + col] = f2b(acc[mi][ni][r]*sc);
        else                Cf[(size_t)(rb+r)*N + col] = acc[mi][ni][r];
      }
    }
  }
}

// ---------------- rowsums (rsq + rsk, one launch) ----------------
__global__ __launch_bounds__(256)
void k_rowsums(const ushort* __restrict__ qkvb,
               float* __restrict__ rsq, float* __restrict__ rsk){
  int i = blockIdx.x*256 + threadIdx.x;
  const ushort* src; float* dst;
  if (i < T_*H_){
    int t = i>>4, g = i&15;
    src = qkvb + (size_t)t*NQ + g*64; dst = rsq + i;
  } else {
    int t = i - T_*H_;
    if (t >= T_) return;
    src = qkvb + (size_t)t*NQ + 1024; dst = rsk + t;
  }
  const uint4* p = (const uint4*)src;
  float s = 0.f;
  #pragma unroll
  for (int j=0;j<8;++j){
    uint4 u = p[j];
    const unsigned int uu[4] = {u.x,u.y,u.z,u.w};
    #pragma unroll
    for (int q=0;q<4;++q){ s += blo(uu[q]); s += bhi(uu[q]); }
  }
  *dst = s;
}

// ---------------- V_exp^T[h][d][t] via MFMA, register-only ----------------
__global__ __launch_bounds__(256)
void k_vexp_mfma(const ushort* __restrict__ qkvb, const ushort* __restrict__ vupT,
                 ushort* __restrict__ vexpT){
  const int h = blockIdx.y, t0 = blockIdx.x*64;
  const int tid = threadIdx.x, lane = tid&63, w = tid>>6;
  const int l15 = lane&15, quad = lane>>4;
  bf16x8 a[2][2], b[4][2];
  #pragma unroll
  for (int mt=0;mt<2;++mt)
    #pragma unroll
    for (int kk=0;kk<2;++kk)
      a[mt][kk] = *(const bf16x8*)(vupT + (size_t)h*D_*L_ + (w*32+mt*16+l15)*64 + kk*32 + quad*8);
  #pragma unroll
  for (int nt=0;nt<4;++nt)
    #pragma unroll
    for (int kk=0;kk<2;++kk)
      b[nt][kk] = *(const bf16x8*)(qkvb + (size_t)(t0+nt*16+l15)*NQ + 1088 + kk*32 + quad*8);
  floatx4 acc[2][4] = {};
  #pragma unroll
  for (int mt=0;mt<2;++mt)
    #pragma unroll
    for (int nt=0;nt<4;++nt)
      #pragma unroll
      for (int kk=0;kk<2;++kk)
        acc[mt][nt] = __builtin_amdgcn_mfma_f32_16x16x32_bf16(a[mt][kk], b[nt][kk], acc[mt][nt], 0,0,0);
  #pragma unroll
  for (int mt=0;mt<2;++mt)
    #pragma unroll
    for (int nt=0;nt<4;++nt)
      #pragma unroll
      for (int r=0;r<4;++r)
        vexpT[((size_t)h*D_ + w*32+mt*16+quad*4+r)*T_ + t0 + nt*16 + l15] = f2b(acc[mt][nt][r]);
}

// ---------------- flash attention, split-S, counted-vmcnt pipeline ---------
// Block = (head, 64-row Q-tile qt, S-chunk c of CH tiles). 4 waves.
// K/V LDS: row-major stride 64, 16B chunk c of row r stored at slot c^(r&7)
// (glds SOURCE-permuted; writes stay contiguous). Ps: unpadded [4][16][64]
// ushort with 16B chunk swizzle chunk^(l15&7) -> 32KB total, 5 blocks/CU.
__global__ __launch_bounds__(256, 4)
void k_attn(const ushort* __restrict__ qkvb,   // [T][1152] bf16
            const float*  __restrict__ rsq,    // [T][16]  (scaled rowsums)
            const float*  __restrict__ rsk,    // [T]
            const ushort* __restrict__ vexpT,  // [16][128][T] bf16
            ushort*       __restrict__ ctx,    // [T][2048] bf16
            ushort*       __restrict__ partO,  // [16][24][4] swizzled 64x128 bf16
            float*        __restrict__ partML, // [16][24][4][64][2]
            int CH){
  __shared__ ushort Ks[64*64];      // 8KB, stride 64, XOR-swizzled chunks
  __shared__ ushort Vts[128*64];    // 16KB, stride 64, XOR-swizzled chunks
  __shared__ ushort Ps[4*16*64];    // 8KB, wave-private rows, chunk-swizzled
  const int h  = blockIdx.y;
  const int bxr = (int)gridDim.x - 1 - (int)blockIdx.x;   // heavy tiles first
  int qt, c;
  if (CH == 8){
    if (bxr < 8){ qt = bxr; c = 0; }
    else if (bxr < 24){ int u = bxr-8;  qt = 8  + (u>>1); c = u&1; }
    else if (bxr < 48){ int u = bxr-24; qt = 16 + u/3;    c = u - (u/3)*3; }
    else               { int u = bxr-48; qt = 24 + (u>>2); c = u&3; }
  } else { qt = bxr; c = 0; }
  const int nct = (qt + CH) / CH;
  const int stBeg = c*CH, stEnd = min(qt, stBeg + CH - 1);
  const int t0 = qt*64;
  const int tid = threadIdx.x, lane = tid & 63, w = tid >> 6;
  const int l15 = lane & 15, quad = lane >> 4;

  auto stageK = [&](int s0k){
    #pragma unroll
    for (int j=0;j<2;++j){ int cc = tid + j*256;
      int row = cc>>3, kc = ((cc&7) ^ (row&7))*8;
      glds16(qkvb + (size_t)(s0k + row)*NQ + 1024 + kc, &Ks[cc*8]); }
  };
  auto stageV = [&](int s0v){
    #pragma unroll
    for (int j=0;j<4;++j){ int cc = tid + j*256;
      int row = cc>>3, sc2 = ((cc&7) ^ (row&7))*8;
      glds16(vexpT + ((size_t)h*128 + row)*T_ + s0v + sc2, &Vts[cc*8]); }
  };

  const int qrow = t0 + w*16 + l15;
  const bf16x8 q0 = *(const bf16x8*)(qkvb + (size_t)qrow*NQ + h*64 + quad*8);
  const bf16x8 q1 = *(const bf16x8*)(qkvb + (size_t)qrow*NQ + h*64 + 32 + quad*8);
  const float rqv = rsq[(size_t)qrow*H_ + h] * 0.5f;      // already *isl*log2e

  float mrun = -INFINITY, lrun = 0.f;
  floatx4 o[8] = {};

  stageK(stBeg*64); stageV(stBeg*64);                // prologue

  for (int st=stBeg; st<=stEnd; ++st){
    const int s0 = st*64;
    const bool more = (st < stEnd);
    // ---- K(st) landed (V(st)'s 4 loads still in flight) ----
    asm volatile("s_waitcnt vmcnt(4)" ::: "memory");
    __builtin_amdgcn_s_barrier();
    __builtin_amdgcn_sched_barrier(0);
    // ---- S^T = K Q^T : lane owns q=l15, s=jt*16+quad*4+r ----
    floatx4 sT[4] = {};
    __builtin_amdgcn_s_setprio(1);
    #pragma unroll
    for (int jt=0;jt<4;++jt){
      const int srow = jt*16 + l15, sx = srow & 7;
      bf16x8 k0f = *(const bf16x8*)(&Ks[srow*64 + (quad^sx)*8]);
      sT[jt] = __builtin_amdgcn_mfma_f32_16x16x32_bf16(k0f, q0, sT[jt], 0,0,0);
      bf16x8 k1f = *(const bf16x8*)(&Ks[srow*64 + ((4+quad)^sx)*8]);
      sT[jt] = __builtin_amdgcn_mfma_f32_16x16x32_bf16(k1f, q1, sT[jt], 0,0,0);
    }
    __builtin_amdgcn_s_setprio(0);
    __builtin_amdgcn_sched_barrier(0);
    __builtin_amdgcn_s_barrier();                  // all K reads done
    if (more) stageK(s0 + 64);                     // K(t+1) under softmax+PV
    // ---- mask + rank-1 band (edge tiles only), in place in sT ----
    float mloc = -3.0e38f;
    if (st >= qt-1){
      #pragma unroll
      for (int jt=0;jt<4;++jt){
        const float4 rk4 = *(const float4*)(rsk + s0 + jt*16 + quad*4);  // broadcast
        #pragma unroll
        for (int r=0;r<4;++r){
          const int sg = s0 + jt*16 + quad*4 + r;
          const int dd = qrow - sg;
          float x = sT[jt][r];
          x = (dd <= 64) ? x + rqv*((const float*)&rk4)[r] : x;
          x = (dd < 0)   ? -3.0e38f : x;
          sT[jt][r] = x; mloc = fmaxf(mloc, x);
        }
      }
    } else {
      #pragma unroll
      for (int jt=0;jt<4;++jt)
        #pragma unroll
        for (int r=0;r<4;++r) mloc = fmaxf(mloc, sT[jt][r]);
    }
    mloc = fmaxf(mloc, __shfl_xor(mloc, 16));
    mloc = fmaxf(mloc, __shfl_xor(mloc, 32));
    // ---- defer-max (T13): keep old max unless it grew by >6 (log2 units) --
    const float mn = (mloc - mrun <= 6.0f) ? mrun : mloc;
    const float al = exp2f(mrun - mn);             // ==1.0 when deferred
    float ss = 0.f;
    #pragma unroll
    for (int jt=0;jt<4;++jt)
      #pragma unroll
      for (int r=0;r<4;++r){
        float p = exp2f(sT[jt][r]-mn); sT[jt][r] = p; ss += p;
      }
    ss += __shfl_xor(ss, 16); ss += __shfl_xor(ss, 32);
    lrun = lrun*al + ss; mrun = mn;
    // ---- P write (wave-private rows, chunk-swizzled; no barrier needed) ----
    #pragma unroll
    for (int jt=0;jt<4;++jt){
      unsigned p01, p23;
      asm volatile("v_cvt_pk_bf16_f32 %0, %1, %2" : "=v"(p01) : "v"(sT[jt][0]), "v"(sT[jt][1]));
      asm volatile("v_cvt_pk_bf16_f32 %0, %1, %2" : "=v"(p23) : "v"(sT[jt][2]), "v"(sT[jt][3]));
      const int chunk = 2*jt + (quad>>1);
      uint2 pw2; pw2.x = p01; pw2.y = p23;
      *(uint2*)(&Ps[(w*16 + l15)*64 + ((chunk ^ (l15&7))<<3) + (quad&1)*4]) = pw2;
    }
    // ---- rescale O rows (skip when no new max anywhere in wave) ----
    if (__any(al < 1.0f)){
      float alr[4];
      #pragma unroll
      for (int r=0;r<4;++r) alr[r] = __shfl(al, quad*4 + r);
      #pragma unroll
      for (int nt=0;nt<8;++nt){
        o[nt][0]*=alr[0]; o[nt][1]*=alr[1]; o[nt][2]*=alr[2]; o[nt][3]*=alr[3];
      }
    }
    // ---- V(st) landed (K(t+1)'s 2 loads still in flight) ----
    __builtin_amdgcn_sched_barrier(0);
    if (more) asm volatile("s_waitcnt vmcnt(2)" ::: "memory");
    else      asm volatile("s_waitcnt vmcnt(0)" ::: "memory");
    __builtin_amdgcn_s_barrier();
    __builtin_amdgcn_sched_barrier(0);
    // ---- O += P V ----
    __builtin_amdgcn_s_setprio(1);
    #pragma unroll
    for (int kks=0;kks<2;++kks){
      const int ch = kks*4 + quad;
      bf16x8 pf = *(const bf16x8*)(&Ps[(w*16 + l15)*64 + ((ch ^ (l15&7))<<3)]);
      #pragma unroll
      for (int nt=0;nt<8;++nt){
        const int vrow = nt*16 + l15, vx = vrow & 7;
        bf16x8 vf = *(const bf16x8*)(&Vts[vrow*64 + ((kks*4+quad)^vx)*8]);
        o[nt] = __builtin_amdgcn_mfma_f32_16x16x32_bf16(pf, vf, o[nt], 0,0,0);
      }
    }
    __builtin_amdgcn_s_setprio(0);
    __builtin_amdgcn_sched_barrier(0);
    if (more){
      __builtin_amdgcn_s_barrier();                // all V reads done
      stageV(s0 + 64);                             // V(t+1) under next QK+softmax
    }
  }
  // ---- epilogue ----
  const float linv = 1.f/lrun;
  float lr4[4];
  #pragma unroll
  for (int r=0;r<4;++r) lr4[r] = __shfl(linv, quad*4 + r);
  if (nct == 1){
    #pragma unroll
    for (int r=0;r<4;++r){
      const int row = t0 + w*16 + quad*4 + r;
      #pragma unroll
      for (int nt=0;nt<8;++nt)
        ctx[(size_t)row*E_ + h*D_ + nt*16 + l15] = f2b(o[nt][r]*lr4[r]);
    }
  } else {
    const int slot = (h*24 + (qt-8))*4 + c;
    ushort* po = partO + (size_t)slot*8192;            // swizzled [w][nt][r][lane]
    #pragma unroll
    for (int nt=0;nt<8;++nt)
      #pragma unroll
      for (int r=0;r<4;++r)
        po[((w*8+nt)*4+r)*64 + quad*16 + l15] = f2b(o[nt][r]*lr4[r]);  // 128B/instr
    if (quad == 0){
      float2 ml; ml.x = mrun; ml.y = lrun;
      ((float2*)partML)[(size_t)slot*64 + w*16 + l15] = ml;
    }
  }
}

// ---------------- merge partials -> ctx (qt >= 8) ----------------
__global__ __launch_bounds__(256)
void k_merge(const ushort* __restrict__ partO, const float* __restrict__ partML,
             ushort* __restrict__ ctx){
  const int h = blockIdx.y, qt = 8 + blockIdx.x;
  const int nct = (qt + 8) / 8;
  const int tid = threadIdx.x;
  const int rg = tid >> 2, d0 = (tid & 3)*32;
  const int w = rg >> 4, quad = (rg >> 2) & 3, rr = rg & 3;
  const int n0 = d0 >> 4;
  const int sbase = (h*24 + (qt-8))*4;
  float m[4], l[4], M = -INFINITY;
  for (int c=0;c<4;++c){
    if (c < nct){
      float2 v = ((const float2*)partML)[(size_t)(sbase+c)*64 + rg];
      m[c]=v.x; l[c]=v.y; M = fmaxf(M, v.x);
    }
  }
  float lt = 0.f, wgt[4];
  for (int c=0;c<4;++c){
    if (c < nct){ wgt[c] = exp2f(m[c]-M)*l[c]; lt += wgt[c]; }
  }
  const float inv = 1.f/lt;
  float acc[32];
  #pragma unroll
  for (int i=0;i<32;++i) acc[i]=0.f;
  for (int c=0;c<4;++c){
    if (c >= nct) break;
    const float sc = wgt[c]*inv;
    const ushort* po = partO + (size_t)(sbase+c)*8192;
    #pragma unroll
    for (int nn=0;nn<2;++nn){
      const ushort* p2 = po + ((w*8 + n0+nn)*4 + rr)*64 + quad*16;
      uint4 u  = *(const uint4*)p2;
      uint4 u2 = *(const uint4*)(p2 + 8);
      const unsigned int uu[8] = {u.x,u.y,u.z,u.w,u2.x,u2.y,u2.z,u2.w};
      #pragma unroll
      for (int q=0;q<8;++q){
        acc[nn*16+q*2]   += sc*blo(uu[q]);
        acc[nn*16+q*2+1] += sc*bhi(uu[q]);
      }
    }
  }
  ushort* dst = ctx + (size_t)(qt*64 + rg)*E_ + h*D_ + d0;
  #pragma unroll
  for (int k=0;k<8;++k){
    ushort4 ov; ov.x=f2b(acc[k*4]); ov.y=f2b(acc[k*4+1]);
    ov.z=f2b(acc[k*4+2]); ov.w=f2b(acc[k*4+3]);
    *(ushort4*)(dst + k*4) = ov;
  }
}

// ---------------- launch ----------------
extern "C" void kernel_launch(void* const* d_in, const int* in_sizes, int n_in,
                              void* d_out, int out_size, void* d_ws, size_t ws_size,
                              hipStream_t stream) {
  const float* hs  = (const float*)d_in[0];
  const float* Wq  = (const float*)d_in[1];
  const float* Wk  = (const float*)d_in[2];
  const float* Wv  = (const float*)d_in[3];
  const float* q2l = (const float*)d_in[4];
  const float* vup = (const float*)d_in[5];
  const float* Wo  = (const float*)d_in[6];
  float* out = (float*)d_out;
  char* ws = (char*)d_ws;

  // workspace layout (bytes) — round-6 proven layout
  ushort* hsb   = (ushort*)(ws + 0);           // [2048][2048] bf16
  ushort* Wqkvb = (ushort*)(ws + 8388608);     // [1152][2048] bf16 (ql|k|v)
  ushort* Wob   = (ushort*)(ws + 13107200);    // [2048][2048] bf16
  ushort* qkvb  = (ushort*)(ws + 21495808);    // [2048][1152] bf16
  ushort* vupT  = (ushort*)(ws + 26214400);    // [16][128][64] bf16
  float*  rsqp  = (float*) (ws + 26476544);    // [2048][16]
  float*  rskp  = (float*) (ws + 26607616);    // [2048]
  ushort* vexpT = (ushort*)(ws + 26615808);    // [16][128][2048] bf16
  ushort* ctxb  = (ushort*)(ws + 35004416);    // [2048][2048] bf16
  ushort* partO = (ushort*)(ws + 43393024);    // [16][24][4] x 8192 bf16 (swizzled)
  float*  partML= (float*) (ws + 68558848);    // [16][24][4][64][2]
  const size_t NEED = 69345280;
  const int CH = (ws_size >= NEED) ? 8 : 32;

  // 1) bf16 conversions (hs, Wo, Wk, Wv) in one launch
  k_f2b4<<<8448, 256, 0, stream>>>(hs, hsb, Wo, Wob,
                                   Wk, Wqkvb + (size_t)1024*E_,
                                   Wv, Wqkvb + (size_t)1088*E_);

  // 2) weight prep
  k_prep_wql<<<dim3(16,2,16), 128, 0, stream>>>(Wq, q2l, Wqkvb);
  k_prep_vupT<<<16, 256, 0, stream>>>(vup, vupT);

  // 3) fused q_latent|k|v GEMM -> qkvb [2048][1152] (ql cols pre-scaled)
  //    64x64 tiles: 576 blocks (2.25/CU) for latency hiding
  gemm_glds<2,2,true><<<dim3(18,32), 256, 0, stream>>>(
      hsb, Wqkvb, nullptr, qkvb, T_, NQ, E_, 0.18033688f);

  // 4) rowsums (one launch)
  k_rowsums<<<136, 256, 0, stream>>>(qkvb, rsqp, rskp);

  // 5) V_exp^T via MFMA
  k_vexp_mfma<<<dim3(32,16), 256, 0, stream>>>(qkvb, vupT, vexpT);

  // 6) flash attention (split-S, pipelined) -> ctx / partials
  k_attn<<<dim3(CH==8 ? 80 : 32, 16), 256, 0, stream>>>(
      qkvb, rsqp, rskp, vexpT, ctxb, partO, partML, CH);

  // 7) merge partials
  if (CH == 8)
    k_merge<<<dim3(24,16), 256, 0, stream>>>(partO, partML, ctxb);

  // 8) out = ctx @ Wo^T (fp32 to d_out): 64x128 tiles, 512 blocks (2/CU)
  gemm_glds<2,4,false><<<dim3(16,32), 256, 0, stream>>>(
      ctxb, Wob, out, nullptr, T_, E_, E_, 1.0f);
}

// Round 6
// 254.545 us; speedup vs baseline: 1.2616x; 1.0694x over previous
//
#include <hip/hip_runtime.h>

// RA_MLA_Attention — MI355X (gfx950). Round 12.
// B=1, T=2048, E=2048, H=16, D=128, L=64, RA_WINDOW=64, RA_ALPHA=0.5
//
// Round-12 changes (GEMMs only; k_attn/rest byte-identical to r11):
//   * gemm_glds2: BK=64 (32 K-steps instead of 64 -> half the vmcnt(0)
//     barrier drains; 2x MFMA per drain) + LDS XOR chunk swizzle
//     (stride-128B rows would be 16-way bank conflict; swizzle via
//     source-permuted glds like k_attn -- also kills the 3.1M conflict
//     cycles the BK=32 version had) + bijective XCD chunk swizzle
//     (same-XCD blocks share A-panel -> L2-local glds, smaller drain).
//   * No sched_barrier / counted vmcnt in GEMM (r8 lesson: let the
//     compiler schedule; structural changes only).

#define T_ 2048
#define E_ 2048
#define H_ 16
#define D_ 128
#define L_ 64
#define NQ 1152            // fused qkv GEMM N (1024 ql | 64 k | 64 v)

typedef float  floatx4 __attribute__((ext_vector_type(4)));
typedef __bf16 bf16x8  __attribute__((ext_vector_type(8)));

__device__ __forceinline__ ushort f2b(float x){           // fp32 -> bf16 bits, RNE
  unsigned int u = __float_as_uint(x);
  u = (u + 0x7fffu + ((u >> 16) & 1u)) >> 16;
  return (ushort)u;
}
__device__ __forceinline__ float blo(unsigned int u){ return __uint_as_float(u << 16); }
__device__ __forceinline__ float bhi(unsigned int u){ return __uint_as_float(u & 0xffff0000u); }

__device__ __forceinline__ void glds16(const ushort* g, ushort* l){
#if __has_builtin(__builtin_amdgcn_global_load_lds)
  __builtin_amdgcn_global_load_lds((const __attribute__((address_space(1))) void*)g,
                                   (__attribute__((address_space(3))) void*)l, 16, 0, 0);
#else
  *(uint4*)l = *(const uint4*)g;
#endif
}

// ---------------- fused fp32 -> bf16 convert (4 tensors, 1 launch) ----------
__global__ __launch_bounds__(256)
void k_f2b4(const float* __restrict__ a, ushort* __restrict__ oa,
            const float* __restrict__ b, ushort* __restrict__ ob,
            const float* __restrict__ c, ushort* __restrict__ oc,
            const float* __restrict__ d, ushort* __restrict__ od){
  int bid = blockIdx.x; const float* src; ushort* dst; int base;
  if (bid < 4096){ src=a; dst=oa; base=bid; }
  else if (bid < 8192){ src=b; dst=ob; base=bid-4096; }
  else if (bid < 8320){ src=c; dst=oc; base=bid-8192; }
  else { src=d; dst=od; base=bid-8320; }
  int i = (base*256 + (int)threadIdx.x)*4;
  float4 v = *(const float4*)(src + i);
  ushort4 o; o.x=f2b(v.x); o.y=f2b(v.y); o.z=f2b(v.z); o.w=f2b(v.w);
  *(ushort4*)(dst + i) = o;
}

// ---------------- fold q_to_latent into Wq:  Wql[(h,l),e] (rows of Wqkvb) ----
__global__ __launch_bounds__(128)
void k_prep_wql(const float* __restrict__ Wq, const float* __restrict__ q2l,
                ushort* __restrict__ Wql){
  const int h = blockIdx.z, lh = blockIdx.y;            // l half: lh*32..lh*32+31
  const int e = blockIdx.x*128 + threadIdx.x;
  const float* qb = q2l + (size_t)h*D_*L_ + lh*32;
  float acc[32];
  #pragma unroll
  for (int i=0;i<32;++i) acc[i]=0.f;
  for (int d=0; d<128; ++d){
    float wv = Wq[(size_t)(h*128+d)*E_ + e];
    #pragma unroll
    for (int i=0;i<32;++i) acc[i] += wv*qb[(size_t)d*64 + i];
  }
  #pragma unroll
  for (int i=0;i<32;++i) Wql[(size_t)(h*64 + lh*32 + i)*E_ + e] = f2b(acc[i]);
}

// ---------------- vupT[h][d][l] = vup[h][l][d], bf16 ----------------
__global__ __launch_bounds__(256)
void k_prep_vupT(const float* __restrict__ vup, ushort* __restrict__ vupT){
  const int h = blockIdx.x, tid = threadIdx.x;
  for (int idx = tid; idx < L_*D_; idx += 256){
    int l = idx >> 7, d = idx & 127;
    vupT[(size_t)h*D_*L_ + d*64 + l] = f2b(vup[(size_t)h*L_*D_ + idx]);
  }
}

// ---------------- BK=64 GEMM: C[M,N] = A[M,K] @ B[N,K]^T --------------------
// 4 waves 2x2; BM=32*MT, BN=32*NT. LDS rows stride 64 ushort (128B) with
// 16B-chunk XOR swizzle: chunk slot s of row r holds global chunk s^(r&7)
// (glds SOURCE-permuted; LDS writes stay linear). Bijective XCD chunk
// swizzle: XCD j processes a contiguous band of logical tiles (A-panel
// stays in its L2). OB16: bf16 out with col-block scale.
template<int MT,int NT,bool OB16>
__global__ __launch_bounds__(256)
void gemm_glds2(const ushort* __restrict__ A, const ushort* __restrict__ B,
                float* __restrict__ Cf, ushort* __restrict__ Cb,
                int M, int N, int K, float scale){
  constexpr int BM = 32*MT, BN = 32*NT;
  constexpr int IA = BM/32, IB = BN/32;     // glds16 per thread per K-step
  __shared__ ushort As[BM*64];
  __shared__ ushort Bs[BN*64];
  const int tid = threadIdx.x, lane = tid&63, wv = tid>>6;
  const int wm = wv & 1, wn = wv >> 1;
  const int l15 = lane&15, quad = lane>>4;
  // XCD chunk swizzle (HW round-robins linear bid across 8 XCDs; remap so
  // XCD j gets logical tiles [j*cpx, (j+1)*cpx) = contiguous m-bands).
  const int nbx = (int)gridDim.x, nwg = nbx*(int)gridDim.y;  // nwg % 8 == 0
  int bid = (int)blockIdx.y*nbx + (int)blockIdx.x;
  bid = (bid & 7)*(nwg >> 3) + (bid >> 3);
  const int m0 = (bid / nbx)*BM, n0 = (bid % nbx)*BN;
  const float sc = (n0 < 1024) ? scale : 1.0f;     // qkv: ql cols scaled
  floatx4 acc[MT][NT] = {};
  for (int k0=0; k0<K; k0+=64){
    __syncthreads();
    #pragma unroll
    for (int j=0;j<IA;++j){
      int cc = j*256 + tid; int row = cc>>3, kc = ((cc&7)^(row&7))*8;
      glds16(A + (size_t)(m0+row)*K + k0 + kc, &As[cc*8]);
    }
    #pragma unroll
    for (int j=0;j<IB;++j){
      int cc = j*256 + tid; int row = cc>>3, kc = ((cc&7)^(row&7))*8;
      glds16(B + (size_t)(n0+row)*K + k0 + kc, &Bs[cc*8]);
    }
    __syncthreads();
    #pragma unroll
    for (int kk=0;kk<2;++kk){
      bf16x8 af[MT], bfr[NT];
      #pragma unroll
      for (int mi=0;mi<MT;++mi){
        const int r = wm*MT*16 + mi*16 + l15;
        af[mi] = *(const bf16x8*)(&As[r*64 + (((kk*4+quad)^(r&7))<<3)]);
      }
      #pragma unroll
      for (int ni=0;ni<NT;++ni){
        const int r = wn*NT*16 + ni*16 + l15;
        bfr[ni] = *(const bf16x8*)(&Bs[r*64 + (((kk*4+quad)^(r&7))<<3)]);
      }
      #pragma unroll
      for (int mi=0;mi<MT;++mi)
        #pragma unroll
        for (int ni=0;ni<NT;++ni)
          acc[mi][ni] = __builtin_amdgcn_mfma_f32_16x16x32_bf16(af[mi], bfr[ni], acc[mi][ni], 0,0,0);
    }
  }
  #pragma unroll
  for (int mi=0;mi<MT;++mi){
    const int rb = m0 + wm*MT*16 + mi*16 + quad*4;
    #pragma unroll
    for (int ni=0;ni<NT;++ni){
      const int col = n0 + wn*NT*16 + ni*16 + l15;
      #pragma unroll
      for (int r=0;r<4;++r){
        if constexpr (OB16) Cb[(size_t)(rb+r)*N + col] = f2b(acc[mi][ni][r]*sc);
        else                Cf[(size_t)(rb+r)*N + col] = acc[mi][ni][r];
      }
    }
  }
}

// ---------------- rowsums (rsq + rsk, one launch) ----------------
__global__ __launch_bounds__(256)
void k_rowsums(const ushort* __restrict__ qkvb,
               float* __restrict__ rsq, float* __restrict__ rsk){
  int i = blockIdx.x*256 + threadIdx.x;
  const ushort* src; float* dst;
  if (i < T_*H_){
    int t = i>>4, g = i&15;
    src = qkvb + (size_t)t*NQ + g*64; dst = rsq + i;
  } else {
    int t = i - T_*H_;
    if (t >= T_) return;
    src = qkvb + (size_t)t*NQ + 1024; dst = rsk + t;
  }
  const uint4* p = (const uint4*)src;
  float s = 0.f;
  #pragma unroll
  for (int j=0;j<8;++j){
    uint4 u = p[j];
    const unsigned int uu[4] = {u.x,u.y,u.z,u.w};
    #pragma unroll
    for (int q=0;q<4;++q){ s += blo(uu[q]); s += bhi(uu[q]); }
  }
  *dst = s;
}

// ---------------- V_exp^T[h][d][t] via MFMA, register-only ----------------
__global__ __launch_bounds__(256)
void k_vexp_mfma(const ushort* __restrict__ qkvb, const ushort* __restrict__ vupT,
                 ushort* __restrict__ vexpT){
  const int h = blockIdx.y, t0 = blockIdx.x*64;
  const int tid = threadIdx.x, lane = tid&63, w = tid>>6;
  const int l15 = lane&15, quad = lane>>4;
  bf16x8 a[2][2], b[4][2];
  #pragma unroll
  for (int mt=0;mt<2;++mt)
    #pragma unroll
    for (int kk=0;kk<2;++kk)
      a[mt][kk] = *(const bf16x8*)(vupT + (size_t)h*D_*L_ + (w*32+mt*16+l15)*64 + kk*32 + quad*8);
  #pragma unroll
  for (int nt=0;nt<4;++nt)
    #pragma unroll
    for (int kk=0;kk<2;++kk)
      b[nt][kk] = *(const bf16x8*)(qkvb + (size_t)(t0+nt*16+l15)*NQ + 1088 + kk*32 + quad*8);
  floatx4 acc[2][4] = {};
  #pragma unroll
  for (int mt=0;mt<2;++mt)
    #pragma unroll
    for (int nt=0;nt<4;++nt)
      #pragma unroll
      for (int kk=0;kk<2;++kk)
        acc[mt][nt] = __builtin_amdgcn_mfma_f32_16x16x32_bf16(a[mt][kk], b[nt][kk], acc[mt][nt], 0,0,0);
  #pragma unroll
  for (int mt=0;mt<2;++mt)
    #pragma unroll
    for (int nt=0;nt<4;++nt)
      #pragma unroll
      for (int r=0;r<4;++r)
        vexpT[((size_t)h*D_ + w*32+mt*16+quad*4+r)*T_ + t0 + nt*16 + l15] = f2b(acc[mt][nt][r]);
}

// ---------------- flash attention, split-S, counted-vmcnt pipeline ---------
// Block = (head, 64-row Q-tile qt, S-chunk c of CH tiles). 4 waves.
// K/V LDS: row-major stride 64, 16B chunk c of row r stored at slot c^(r&7)
// (glds SOURCE-permuted; writes stay contiguous). Ps: unpadded [4][16][64]
// ushort with 16B chunk swizzle chunk^(l15&7) -> 32KB total.
__global__ __launch_bounds__(256, 4)
void k_attn(const ushort* __restrict__ qkvb,   // [T][1152] bf16
            const float*  __restrict__ rsq,    // [T][16]  (scaled rowsums)
            const float*  __restrict__ rsk,    // [T]
            const ushort* __restrict__ vexpT,  // [16][128][T] bf16
            ushort*       __restrict__ ctx,    // [T][2048] bf16
            ushort*       __restrict__ partO,  // [16][24][4] swizzled 64x128 bf16
            float*        __restrict__ partML, // [16][24][4][64][2]
            int CH){
  __shared__ ushort Ks[64*64];      // 8KB, stride 64, XOR-swizzled chunks
  __shared__ ushort Vts[128*64];    // 16KB, stride 64, XOR-swizzled chunks
  __shared__ ushort Ps[4*16*64];    // 8KB, wave-private rows, chunk-swizzled
  const int h  = blockIdx.y;
  const int bxr = (int)gridDim.x - 1 - (int)blockIdx.x;   // heavy tiles first
  int qt, c;
  if (CH == 8){
    if (bxr < 8){ qt = bxr; c = 0; }
    else if (bxr < 24){ int u = bxr-8;  qt = 8  + (u>>1); c = u&1; }
    else if (bxr < 48){ int u = bxr-24; qt = 16 + u/3;    c = u - (u/3)*3; }
    else               { int u = bxr-48; qt = 24 + (u>>2); c = u&3; }
  } else { qt = bxr; c = 0; }
  const int nct = (qt + CH) / CH;
  const int stBeg = c*CH, stEnd = min(qt, stBeg + CH - 1);
  const int t0 = qt*64;
  const int tid = threadIdx.x, lane = tid & 63, w = tid >> 6;
  const int l15 = lane & 15, quad = lane >> 4;

  auto stageK = [&](int s0k){
    #pragma unroll
    for (int j=0;j<2;++j){ int cc = tid + j*256;
      int row = cc>>3, kc = ((cc&7) ^ (row&7))*8;
      glds16(qkvb + (size_t)(s0k + row)*NQ + 1024 + kc, &Ks[cc*8]); }
  };
  auto stageV = [&](int s0v){
    #pragma unroll
    for (int j=0;j<4;++j){ int cc = tid + j*256;
      int row = cc>>3, sc2 = ((cc&7) ^ (row&7))*8;
      glds16(vexpT + ((size_t)h*128 + row)*T_ + s0v + sc2, &Vts[cc*8]); }
  };

  const int qrow = t0 + w*16 + l15;
  const bf16x8 q0 = *(const bf16x8*)(qkvb + (size_t)qrow*NQ + h*64 + quad*8);
  const bf16x8 q1 = *(const bf16x8*)(qkvb + (size_t)qrow*NQ + h*64 + 32 + quad*8);
  const float rqv = rsq[(size_t)qrow*H_ + h] * 0.5f;      // already *isl*log2e

  float mrun = -INFINITY, lrun = 0.f;
  floatx4 o[8] = {};

  stageK(stBeg*64); stageV(stBeg*64);                // prologue

  for (int st=stBeg; st<=stEnd; ++st){
    const int s0 = st*64;
    const bool more = (st < stEnd);
    // ---- K(st) landed (V(st)'s 4 loads still in flight) ----
    asm volatile("s_waitcnt vmcnt(4)" ::: "memory");
    __builtin_amdgcn_s_barrier();
    __builtin_amdgcn_sched_barrier(0);
    // ---- S^T = K Q^T : lane owns q=l15, s=jt*16+quad*4+r ----
    floatx4 sT[4] = {};
    __builtin_amdgcn_s_setprio(1);
    #pragma unroll
    for (int jt=0;jt<4;++jt){
      const int srow = jt*16 + l15, sx = srow & 7;
      bf16x8 k0f = *(const bf16x8*)(&Ks[srow*64 + (quad^sx)*8]);
      sT[jt] = __builtin_amdgcn_mfma_f32_16x16x32_bf16(k0f, q0, sT[jt], 0,0,0);
      bf16x8 k1f = *(const bf16x8*)(&Ks[srow*64 + ((4+quad)^sx)*8]);
      sT[jt] = __builtin_amdgcn_mfma_f32_16x16x32_bf16(k1f, q1, sT[jt], 0,0,0);
    }
    __builtin_amdgcn_s_setprio(0);
    __builtin_amdgcn_sched_barrier(0);
    __builtin_amdgcn_s_barrier();                  // all K reads done
    if (more) stageK(s0 + 64);                     // K(t+1) under softmax+PV
    // ---- mask + rank-1 band (edge tiles only), in place in sT ----
    float mloc = -3.0e38f;
    if (st >= qt-1){
      #pragma unroll
      for (int jt=0;jt<4;++jt){
        const float4 rk4 = *(const float4*)(rsk + s0 + jt*16 + quad*4);  // broadcast
        #pragma unroll
        for (int r=0;r<4;++r){
          const int sg = s0 + jt*16 + quad*4 + r;
          const int dd = qrow - sg;
          float x = sT[jt][r];
          x = (dd <= 64) ? x + rqv*((const float*)&rk4)[r] : x;
          x = (dd < 0)   ? -3.0e38f : x;
          sT[jt][r] = x; mloc = fmaxf(mloc, x);
        }
      }
    } else {
      #pragma unroll
      for (int jt=0;jt<4;++jt)
        #pragma unroll
        for (int r=0;r<4;++r) mloc = fmaxf(mloc, sT[jt][r]);
    }
    mloc = fmaxf(mloc, __shfl_xor(mloc, 16));
    mloc = fmaxf(mloc, __shfl_xor(mloc, 32));
    // ---- defer-max (T13): keep old max unless it grew by >6 (log2 units) --
    const float mn = (mloc - mrun <= 6.0f) ? mrun : mloc;
    const float al = exp2f(mrun - mn);             // ==1.0 when deferred
    float ss = 0.f;
    #pragma unroll
    for (int jt=0;jt<4;++jt)
      #pragma unroll
      for (int r=0;r<4;++r){
        float p = exp2f(sT[jt][r]-mn); sT[jt][r] = p; ss += p;
      }
    ss += __shfl_xor(ss, 16); ss += __shfl_xor(ss, 32);
    lrun = lrun*al + ss; mrun = mn;
    // ---- P write (wave-private rows, chunk-swizzled; no barrier needed) ----
    #pragma unroll
    for (int jt=0;jt<4;++jt){
      unsigned p01, p23;
      asm volatile("v_cvt_pk_bf16_f32 %0, %1, %2" : "=v"(p01) : "v"(sT[jt][0]), "v"(sT[jt][1]));
      asm volatile("v_cvt_pk_bf16_f32 %0, %1, %2" : "=v"(p23) : "v"(sT[jt][2]), "v"(sT[jt][3]));
      const int chunk = 2*jt + (quad>>1);
      uint2 pw2; pw2.x = p01; pw2.y = p23;
      *(uint2*)(&Ps[(w*16 + l15)*64 + ((chunk ^ (l15&7))<<3) + (quad&1)*4]) = pw2;
    }
    // ---- rescale O rows (skip when no new max anywhere in wave) ----
    if (__any(al < 1.0f)){
      float alr[4];
      #pragma unroll
      for (int r=0;r<4;++r) alr[r] = __shfl(al, quad*4 + r);
      #pragma unroll
      for (int nt=0;nt<8;++nt){
        o[nt][0]*=alr[0]; o[nt][1]*=alr[1]; o[nt][2]*=alr[2]; o[nt][3]*=alr[3];
      }
    }
    // ---- V(st) landed (K(t+1)'s 2 loads still in flight) ----
    __builtin_amdgcn_sched_barrier(0);
    if (more) asm volatile("s_waitcnt vmcnt(2)" ::: "memory");
    else      asm volatile("s_waitcnt vmcnt(0)" ::: "memory");
    __builtin_amdgcn_s_barrier();
    __builtin_amdgcn_sched_barrier(0);
    // ---- O += P V ----
    __builtin_amdgcn_s_setprio(1);
    #pragma unroll
    for (int kks=0;kks<2;++kks){
      const int ch = kks*4 + quad;
      bf16x8 pf = *(const bf16x8*)(&Ps[(w*16 + l15)*64 + ((ch ^ (l15&7))<<3)]);
      #pragma unroll
      for (int nt=0;nt<8;++nt){
        const int vrow = nt*16 + l15, vx = vrow & 7;
        bf16x8 vf = *(const bf16x8*)(&Vts[vrow*64 + ((kks*4+quad)^vx)*8]);
        o[nt] = __builtin_amdgcn_mfma_f32_16x16x32_bf16(pf, vf, o[nt], 0,0,0);
      }
    }
    __builtin_amdgcn_s_setprio(0);
    __builtin_amdgcn_sched_barrier(0);
    if (more){
      __builtin_amdgcn_s_barrier();                // all V reads done
      stageV(s0 + 64);                             // V(t+1) under next QK+softmax
    }
  }
  // ---- epilogue ----
  const float linv = 1.f/lrun;
  float lr4[4];
  #pragma unroll
  for (int r=0;r<4;++r) lr4[r] = __shfl(linv, quad*4 + r);
  if (nct == 1){
    #pragma unroll
    for (int r=0;r<4;++r){
      const int row = t0 + w*16 + quad*4 + r;
      #pragma unroll
      for (int nt=0;nt<8;++nt)
        ctx[(size_t)row*E_ + h*D_ + nt*16 + l15] = f2b(o[nt][r]*lr4[r]);
    }
  } else {
    const int slot = (h*24 + (qt-8))*4 + c;
    ushort* po = partO + (size_t)slot*8192;            // swizzled [w][nt][r][lane]
    #pragma unroll
    for (int nt=0;nt<8;++nt)
      #pragma unroll
      for (int r=0;r<4;++r)
        po[((w*8+nt)*4+r)*64 + quad*16 + l15] = f2b(o[nt][r]*lr4[r]);  // 128B/instr
    if (quad == 0){
      float2 ml; ml.x = mrun; ml.y = lrun;
      ((float2*)partML)[(size_t)slot*64 + w*16 + l15] = ml;
    }
  }
}

// ---------------- merge partials -> ctx (qt >= 8) ----------------
__global__ __launch_bounds__(256)
void k_merge(const ushort* __restrict__ partO, const float* __restrict__ partML,
             ushort* __restrict__ ctx){
  const int h = blockIdx.y, qt = 8 + blockIdx.x;
  const int nct = (qt + 8) / 8;
  const int tid = threadIdx.x;
  const int rg = tid >> 2, d0 = (tid & 3)*32;
  const int w = rg >> 4, quad = (rg >> 2) & 3, rr = rg & 3;
  const int n0 = d0 >> 4;
  const int sbase = (h*24 + (qt-8))*4;
  float m[4], l[4], M = -INFINITY;
  for (int c=0;c<4;++c){
    if (c < nct){
      float2 v = ((const float2*)partML)[(size_t)(sbase+c)*64 + rg];
      m[c]=v.x; l[c]=v.y; M = fmaxf(M, v.x);
    }
  }
  float lt = 0.f, wgt[4];
  for (int c=0;c<4;++c){
    if (c < nct){ wgt[c] = exp2f(m[c]-M)*l[c]; lt += wgt[c]; }
  }
  const float inv = 1.f/lt;
  float acc[32];
  #pragma unroll
  for (int i=0;i<32;++i) acc[i]=0.f;
  for (int c=0;c<4;++c){
    if (c >= nct) break;
    const float sc = wgt[c]*inv;
    const ushort* po = partO + (size_t)(sbase+c)*8192;
    #pragma unroll
    for (int nn=0;nn<2;++nn){
      const ushort* p2 = po + ((w*8 + n0+nn)*4 + rr)*64 + quad*16;
      uint4 u  = *(const uint4*)p2;
      uint4 u2 = *(const uint4*)(p2 + 8);
      const unsigned int uu[8] = {u.x,u.y,u.z,u.w,u2.x,u2.y,u2.z,u2.w};
      #pragma unroll
      for (int q=0;q<8;++q){
        acc[nn*16+q*2]   += sc*blo(uu[q]);
        acc[nn*16+q*2+1] += sc*bhi(uu[q]);
      }
    }
  }
  ushort* dst = ctx + (size_t)(qt*64 + rg)*E_ + h*D_ + d0;
  #pragma unroll
  for (int k=0;k<8;++k){
    ushort4 ov; ov.x=f2b(acc[k*4]); ov.y=f2b(acc[k*4+1]);
    ov.z=f2b(acc[k*4+2]); ov.w=f2b(acc[k*4+3]);
    *(ushort4*)(dst + k*4) = ov;
  }
}

// ---------------- launch ----------------
extern "C" void kernel_launch(void* const* d_in, const int* in_sizes, int n_in,
                              void* d_out, int out_size, void* d_ws, size_t ws_size,
                              hipStream_t stream) {
  const float* hs  = (const float*)d_in[0];
  const float* Wq  = (const float*)d_in[1];
  const float* Wk  = (const float*)d_in[2];
  const float* Wv  = (const float*)d_in[3];
  const float* q2l = (const float*)d_in[4];
  const float* vup = (const float*)d_in[5];
  const float* Wo  = (const float*)d_in[6];
  float* out = (float*)d_out;
  char* ws = (char*)d_ws;

  // workspace layout (bytes) — round-6 proven layout
  ushort* hsb   = (ushort*)(ws + 0);           // [2048][2048] bf16
  ushort* Wqkvb = (ushort*)(ws + 8388608);     // [1152][2048] bf16 (ql|k|v)
  ushort* Wob   = (ushort*)(ws + 13107200);    // [2048][2048] bf16
  ushort* qkvb  = (ushort*)(ws + 21495808);    // [2048][1152] bf16
  ushort* vupT  = (ushort*)(ws + 26214400);    // [16][128][64] bf16
  float*  rsqp  = (float*) (ws + 26476544);    // [2048][16]
  float*  rskp  = (float*) (ws + 26607616);    // [2048]
  ushort* vexpT = (ushort*)(ws + 26615808);    // [16][128][2048] bf16
  ushort* ctxb  = (ushort*)(ws + 35004416);    // [2048][2048] bf16
  ushort* partO = (ushort*)(ws + 43393024);    // [16][24][4] x 8192 bf16 (swizzled)
  float*  partML= (float*) (ws + 68558848);    // [16][24][4][64][2]
  const size_t NEED = 69345280;
  const int CH = (ws_size >= NEED) ? 8 : 32;

  // 1) bf16 conversions (hs, Wo, Wk, Wv) in one launch
  k_f2b4<<<8448, 256, 0, stream>>>(hs, hsb, Wo, Wob,
                                   Wk, Wqkvb + (size_t)1024*E_,
                                   Wv, Wqkvb + (size_t)1088*E_);

  // 2) weight prep
  k_prep_wql<<<dim3(16,2,16), 128, 0, stream>>>(Wq, q2l, Wqkvb);
  k_prep_vupT<<<16, 256, 0, stream>>>(vup, vupT);

  // 3) fused q_latent|k|v GEMM -> qkvb [2048][1152] (ql cols pre-scaled)
  //    64x64 tiles, BK=64: 576 blocks (2.25/CU)
  gemm_glds2<2,2,true><<<dim3(18,32), 256, 0, stream>>>(
      hsb, Wqkvb, nullptr, qkvb, T_, NQ, E_, 0.18033688f);

  // 4) rowsums (one launch)
  k_rowsums<<<136, 256, 0, stream>>>(qkvb, rsqp, rskp);

  // 5) V_exp^T via MFMA
  k_vexp_mfma<<<dim3(32,16), 256, 0, stream>>>(qkvb, vupT, vexpT);

  // 6) flash attention (split-S, pipelined) -> ctx / partials
  k_attn<<<dim3(CH==8 ? 80 : 32, 16), 256, 0, stream>>>(
      qkvb, rsqp, rskp, vexpT, ctxb, partO, partML, CH);

  // 7) merge partials
  if (CH == 8)
    k_merge<<<dim3(24,16), 256, 0, stream>>>(partO, partML, ctxb);

  // 8) out = ctx @ Wo^T (fp32 to d_out): 64x128 tiles, BK=64, 512 blocks
  gemm_glds2<2,4,false><<<dim3(16,32), 256, 0, stream>>>(
      ctxb, Wob, out, nullptr, T_, E_, E_, 1.0f);
}